// Round 12
// baseline (102.633 us; speedup 1.0000x reference)
//
#include <hip/hip_runtime.h>
#include <math.h>

typedef __attribute__((ext_vector_type(4)))  float f32x4;
typedef __attribute__((ext_vector_type(8)))  short short8;
typedef __attribute__((ext_vector_type(16))) float f32x16;

#define B_  16
#define C_  256
#define N_  256
#define O_  256
#define T_  8192
#define L_  64
#define NC_ 128

// async global->LDS, 16B per lane; lds base wave-uniform (HW adds lane*16)
#define GLL16(gptr, lptr) \
  __builtin_amdgcn_global_load_lds((const __attribute__((address_space(1))) void*)(gptr), \
                                   (__attribute__((address_space(3))) void*)(lptr), 16, 0, 0)

__device__ inline unsigned short f2bf(float x) {
    unsigned u = __float_as_uint(x);
    u += 0x7fff + ((u >> 16) & 1);
    return (unsigned short)(u >> 16);
}
__device__ inline float bf2f(unsigned short h) {
    return __uint_as_float(((unsigned)h) << 16);
}
__device__ inline unsigned cvtpk(float a, float b) {   // {lo:bf16(a), hi:bf16(b)}
    unsigned r;
    asm("v_cvt_pk_bf16_f32 %0, %1, %2" : "=v"(r) : "v"(a), "v"(b));
    return r;
}
__device__ inline f32x16 zero16() {
    f32x16 z;
    #pragma unroll
    for (int i = 0; i < 16; ++i) z[i] = 0.f;
    return z;
}

// ---------------------------------------------------------------------------
// prep: Ad, AL=Ad^64, MFMA b-fragment streams for Bd and C.
//   idx = (((kk*8 + nt)*2 + s)*64 + l)*8 + j
// ---------------------------------------------------------------------------
__global__ __launch_bounds__(256) void k_prep(
    const float* __restrict__ raw_lambda, const float* __restrict__ B_c,
    const float* __restrict__ Cmat,
    float* __restrict__ Ad, float* __restrict__ AL,
    unsigned short* __restrict__ BdKf, unsigned short* __restrict__ CKf)
{
    const int r = blockIdx.x;
    const int t = threadIdx.x;
    const int kk = r >> 5, ri = r & 31;
    const int s = ri >> 4, hi = (ri >> 3) & 1, j = ri & 7;
    const int nt = t >> 5, l = (hi << 5) | (t & 31);
    const int idx = (((kk * 8 + nt) * 2 + s) * 64 + l) * 8 + j;

    if (blockIdx.y == 0) {
        const float x  = raw_lambda[t];
        const float sp = (x > 20.f) ? x : log1pf(expf(x));
        const float lam = -sp;
        const float ad  = expf(lam);
        const float factor = (fabsf(lam) > 1e-6f) ? (ad - 1.f) / lam : 1.f;
        if (r == 0) {
            Ad[t] = ad;
            float al = ad;
            #pragma unroll
            for (int i = 0; i < 6; ++i) al *= al;
            AL[t] = al;
        }
        BdKf[idx] = f2bf(B_c[r * N_ + t] * factor);
    } else {
        CKf[idx] = f2bf(Cmat[r * O_ + t]);
    }
}

// B-frag direct-from-L2 load (lane-linear stream, coalesced 1 KB/wave-inst)
#define LDFRAG(MAT, kk, buf) { \
    _Pragma("unroll") \
    for (int q_ = 0; q_ < 2; ++q_) \
        _Pragma("unroll") \
        for (int s_ = 0; s_ < 2; ++s_) \
            fb[buf][q_ * 2 + s_] = *(const short8*)( \
                (MAT) + ((((kk) * 8 + 2 * w + q_) * 2 + s_) * 64 + l) * 8); }

// ---------------------------------------------------------------------------
// Phase A (v12 = v11 with SHFL-FREE u packing): each thread owns a c-pair
// (rows 2p, 2p+1) at one t4 — loads both NT float4 directly, packs with
// cvtpk, writes 4 LDS dwords. Zero cross-lane ops; same values/addresses.
// ---------------------------------------------------------------------------
__global__ __launch_bounds__(256, 3) void k_phaseA(
    const float* __restrict__ u, const unsigned short* __restrict__ BdKf,
    const float* __restrict__ Ad, float* __restrict__ p_last,
    unsigned short* __restrict__ X, int doX)
{
    __shared__ __align__(16) unsigned short ut[16896];   // [64][264] swizzled

    const int k = blockIdx.x, b = blockIdx.y;
    const int tid = threadIdx.x;
    const int w = tid >> 6, l = tid & 63, lo = l & 31, hi = l >> 5;
    const float* ub = u + (size_t)b * C_ * T_ + k * L_;

    const float adq0 = Ad[(2 * w + 0) * 32 + lo];
    const float adq1 = Ad[(2 * w + 1) * 32 + lo];

    // ---- stage u: 16 NT float4 loads (8 c-pairs) in flight, cvtpk pack ----
    {
        f32x4 va[8], vb[8];
        #pragma unroll
        for (int q = 0; q < 8; ++q) {
            const int idx = q * 256 + tid;
            const int p = idx >> 4, t4 = idx & 15;     // c-pair, t-quad
            const float* base = ub + (size_t)(2 * p) * T_ + t4 * 4;
            va[q] = __builtin_nontemporal_load((const f32x4*)(base));
            vb[q] = __builtin_nontemporal_load((const f32x4*)(base + T_));
        }
        unsigned* ud = (unsigned*)ut;
        #pragma unroll
        for (int q = 0; q < 8; ++q) {
            const int idx = q * 256 + tid;
            const int p = idx >> 4, t4 = idx & 15;
            const int nb = p >> 2, jd = p & 3;
            #pragma unroll
            for (int r = 0; r < 4; ++r) {
                const int tA = 4 * t4 + r;
                const int xsw = (tA >> 3) & 3;
                ud[tA * 132 + (((nb ^ xsw) << 2) | jd)] = cvtpk(va[q][r], vb[q][r]);
            }
        }
    }
    __syncthreads();

    // ---- GEMM1: barrier-free; Bd frags direct from L2, 2-ahead prefetch ----
    f32x16 a00 = zero16(), a01 = zero16(), a10 = zero16(), a11 = zero16();
    {
        short8 fb[3][4];
        LDFRAG(BdKf, 0, 0)
        LDFRAG(BdKf, 1, 1)
        #pragma unroll
        for (int kk = 0; kk < 8; ++kk) {
            if (kk < 6) LDFRAG(BdKf, kk + 2, (kk + 2) % 3)
            #pragma unroll
            for (int s = 0; s < 2; ++s) {
                const int blk8 = kk * 4 + s * 2 + hi;
                const int tA2 = lo, tB2 = 32 + lo;
                const short8 fa0 = *(const short8*)(ut + tA2 * 264 + ((blk8 ^ ((tA2 >> 3) & 3)) << 3));
                const short8 fa1 = *(const short8*)(ut + tB2 * 264 + ((blk8 ^ ((tB2 >> 3) & 3)) << 3));
                const short8 fb0 = fb[kk % 3][0 * 2 + s];
                const short8 fb1 = fb[kk % 3][1 * 2 + s];
                a00 = __builtin_amdgcn_mfma_f32_32x32x16_bf16(fa0, fb0, a00, 0, 0, 0);
                a01 = __builtin_amdgcn_mfma_f32_32x32x16_bf16(fa0, fb1, a01, 0, 0, 0);
                a10 = __builtin_amdgcn_mfma_f32_32x32x16_bf16(fa1, fb0, a10, 0, 0, 0);
                a11 = __builtin_amdgcn_mfma_f32_32x32x16_bf16(fa1, fb1, a11, 0, 0, 0);
            }
        }
    }

    // ---- X store: packed bf16, frag layout, coalesced dwordx4 ----
    if (doX) {
        unsigned* Xd = (unsigned*)X + (size_t)(k * B_ + b) * 8192;
        #pragma unroll
        for (int f = 0; f < 4; ++f) {
            const f32x16 a = (f == 0) ? a00 : (f == 1) ? a01 : (f == 2) ? a10 : a11;
            unsigned dw[8];
            #pragma unroll
            for (int d = 0; d < 8; ++d)
                dw[d] = cvtpk(a[2 * d], a[2 * d + 1]);
            unsigned* base = Xd + w * 2048 + f * 512 + l * 4;
            *(int4*)(base)       = *(const int4*)&dw[0];
            *(int4*)(base + 256) = *(const int4*)&dw[4];
        }
    }

    // ---- p_last in-register (row map: t = tt*32 + (reg&3) + 8*(reg>>2) + 4*hi) ----
    {
        float p[2];
        #pragma unroll
        for (int q = 0; q < 2; ++q) {
            const float ad = q ? adq1 : adq0;
            const float ad2 = ad * ad, ad4 = ad2 * ad2, ad8 = ad4 * ad4;
            const float ad16 = ad8 * ad8, ad32 = ad16 * ad16;
            float full[2];
            #pragma unroll
            for (int tt = 0; tt < 2; ++tt) {
                const f32x16 a = (tt == 0) ? (q == 0 ? a00 : a01)
                                           : (q == 0 ? a10 : a11);
                float v2[4];
                #pragma unroll
                for (int g = 0; g < 4; ++g)
                    v2[g] = fmaf(fmaf(fmaf(a[4*g], ad, a[4*g+1]), ad, a[4*g+2]), ad, a[4*g+3]);
                const float H = fmaf(fmaf(fmaf(v2[0], ad8, v2[1]), ad8, v2[2]), ad8, v2[3]);
                float P = hi ? H : H * ad4;
                P += __shfl_xor(P, 32);
                full[tt] = P;
            }
            p[q] = fmaf(full[0], ad32, full[1]);
        }
        if (hi == 0) {
            float* dst = p_last + (size_t)(k * B_ + b) * N_;
            dst[(2 * w + 0) * 32 + lo] = p[0];
            dst[(2 * w + 1) * 32 + lo] = p[1];
        }
    }
}

// ---------------------------------------------------------------------------
// Phase B: carry scan over chunks, LDS-prefetched.
// ---------------------------------------------------------------------------
__global__ __launch_bounds__(256) void k_phaseB(
    const float* __restrict__ p_last, const float* __restrict__ AL,
    float* __restrict__ carry)
{
    __shared__ float buf[32 * 256];
    const int b = blockIdx.x, n = threadIdx.x;
    const float al = AL[n];
    float cur = 0.f;
    for (int kc = 0; kc < 4; ++kc) {
        __syncthreads();
        #pragma unroll
        for (int q = 0; q < 32; ++q)
            buf[q * 256 + n] = p_last[((size_t)(kc * 32 + q) * B_ + b) * N_ + n];
        __syncthreads();
        #pragma unroll
        for (int q = 0; q < 32; ++q) {
            carry[((size_t)(kc * 32 + q) * B_ + b) * N_ + n] = cur;
            cur = fmaf(cur, al, buf[q * 256 + n]);
        }
    }
}

// ---------------------------------------------------------------------------
// Phase C (v12 = v11 unchanged): GLL16 X -> LDS; column gather; scan ->
// swizzled states (in place); barrier-free GEMM2 with direct L2 C-frag loads.
// ---------------------------------------------------------------------------
__global__ __launch_bounds__(256, 3) void k_phaseC(
    const unsigned short* __restrict__ X, const unsigned short* __restrict__ CKf,
    const float* __restrict__ Ad, const float* __restrict__ carry,
    float* __restrict__ y)
{
    __shared__ __align__(16) unsigned short xs[16896];  // X image -> states [64][264]

    const int k = blockIdx.x, b = blockIdx.y;
    const int tid = threadIdx.x;
    const int w = tid >> 6, l = tid & 63, lo = l & 31, hi = l >> 5;
    const int t0 = k * L_;

    {
        const char* src = (const char*)X + (size_t)(k * B_ + b) * 32768;
        #pragma unroll
        for (int q = 0; q < 8; ++q)
            GLL16(src + q * 4096 + w * 1024 + (l << 4),
                  (char*)xs + q * 4096 + w * 1024);
    }
    const float cv = carry[(size_t)(k * B_ + b) * N_ + tid];
    const float ad = Ad[tid];
    __syncthreads();

    // gather this thread's column (n = tid) from frag-layout X
    unsigned arr[2][2][8];   // [tt][h][dw]
    {
        const unsigned* xd = (const unsigned*)xs;
        const int w2 = tid >> 6, q2 = (tid >> 5) & 1, lo2 = tid & 31;
        #pragma unroll
        for (int tt = 0; tt < 2; ++tt)
            #pragma unroll
            for (int h2 = 0; h2 < 2; ++h2) {
                const unsigned* p = xd + w2 * 2048 + (tt * 2 + q2) * 512
                                       + (h2 * 32 + lo2) * 4;
                *(int4*)&arr[tt][h2][0] = *(const int4*)(p);
                *(int4*)&arr[tt][h2][4] = *(const int4*)(p + 256);
            }
    }
    __syncthreads();   // all X reads done before states overwrite

    // scan + write states [64][264] with col-block XOR swizzle
    {
        const int nb = tid >> 3, nl = tid & 7;
        float s = cv;
        #pragma unroll
        for (int tt = 0; tt < 2; ++tt)
            #pragma unroll
            for (int g = 0; g < 4; ++g)
                #pragma unroll
                for (int h2 = 0; h2 < 2; ++h2) {
                    const unsigned d0 = arr[tt][h2][2 * g];
                    const unsigned d1 = arr[tt][h2][2 * g + 1];
                    const int tb = tt * 32 + 8 * g + 4 * h2;
                    const int swz = (((nb ^ ((tb >> 3) & 3)) << 3) | nl);
                    s = fmaf(s, ad, bf2f((unsigned short)(d0 & 0xffff)));
                    xs[(tb + 0) * 264 + swz] = f2bf(s);
                    s = fmaf(s, ad, bf2f((unsigned short)(d0 >> 16)));
                    xs[(tb + 1) * 264 + swz] = f2bf(s);
                    s = fmaf(s, ad, bf2f((unsigned short)(d1 & 0xffff)));
                    xs[(tb + 2) * 264 + swz] = f2bf(s);
                    s = fmaf(s, ad, bf2f((unsigned short)(d1 >> 16)));
                    xs[(tb + 3) * 264 + swz] = f2bf(s);
                }
    }
    __syncthreads();

    // ---- GEMM2: barrier-free; C-frags direct from L2, 2-ahead prefetch ----
    f32x16 c00 = zero16(), c01 = zero16(), c10 = zero16(), c11 = zero16();
    {
        short8 fb[3][4];
        LDFRAG(CKf, 0, 0)
        LDFRAG(CKf, 1, 1)
        #pragma unroll
        for (int kk = 0; kk < 8; ++kk) {
            if (kk < 6) LDFRAG(CKf, kk + 2, (kk + 2) % 3)
            #pragma unroll
            for (int s = 0; s < 2; ++s) {
                short8 fa[2];
                #pragma unroll
                for (int tt = 0; tt < 2; ++tt) {
                    const int t = tt * 32 + lo;
                    const int blk = (kk * 4 + s * 2 + hi) ^ ((t >> 3) & 3);
                    fa[tt] = *(const short8*)(xs + t * 264 + blk * 8);
                }
                const short8 fb0 = fb[kk % 3][0 * 2 + s];
                const short8 fb1 = fb[kk % 3][1 * 2 + s];
                c00 = __builtin_amdgcn_mfma_f32_32x32x16_bf16(fa[0], fb0, c00, 0, 0, 0);
                c01 = __builtin_amdgcn_mfma_f32_32x32x16_bf16(fa[0], fb1, c01, 0, 0, 0);
                c10 = __builtin_amdgcn_mfma_f32_32x32x16_bf16(fa[1], fb0, c10, 0, 0, 0);
                c11 = __builtin_amdgcn_mfma_f32_32x32x16_bf16(fa[1], fb1, c11, 0, 0, 0);
            }
        }
    }

    // ---- y store ----
    #pragma unroll
    for (int tt = 0; tt < 2; ++tt)
        #pragma unroll
        for (int q = 0; q < 2; ++q) {
            const f32x16 a = (tt == 0) ? (q == 0 ? c00 : c01) : (q == 0 ? c10 : c11);
            const int o = (2 * w + q) * 32 + lo;
            float* yo = y + ((size_t)b * O_ + o) * T_ + t0 + tt * 32 + hi * 4;
            #pragma unroll
            for (int g = 0; g < 4; ++g) {
                float4 vv;
                vv.x = a[g * 4 + 0]; vv.y = a[g * 4 + 1];
                vv.z = a[g * 4 + 2]; vv.w = a[g * 4 + 3];
                *(float4*)(yo + g * 8) = vv;
            }
        }
}

// ---------------------------------------------------------------------------
// Fallback Phase C (recompute GEMM1) — used only if ws too small.
// ---------------------------------------------------------------------------
__device__ __forceinline__ void gemm1_rc(
    const float* __restrict__ u, const unsigned short* __restrict__ BdKf,
    int b, int k, unsigned short* xs, unsigned short* ut, unsigned short* bb)
{
    const int tid = threadIdx.x;
    const int w = tid >> 6, l = tid & 63, lo = l & 31, hi = l >> 5;
    const int t0 = k * L_;
    f32x16 a00 = zero16(), a01 = zero16(), a10 = zero16(), a11 = zero16();
    for (int kk = 0; kk < 8; ++kk) {
        #pragma unroll
        for (int q = 0; q < 2; ++q) {
            const int i = q * 256 + tid, cl = i >> 4, t4 = i & 15;
            const float4 v = *(const float4*)(
                u + ((size_t)b * C_ + kk * 32 + cl) * T_ + t0 + t4 * 4);
            ut[(t4 * 4 + 0) * 40 + cl] = f2bf(v.x);
            ut[(t4 * 4 + 1) * 40 + cl] = f2bf(v.y);
            ut[(t4 * 4 + 2) * 40 + cl] = f2bf(v.z);
            ut[(t4 * 4 + 3) * 40 + cl] = f2bf(v.w);
        }
        {
            const unsigned short* src = BdKf + kk * 8192;
            #pragma unroll
            for (int q = 0; q < 4; ++q) {
                const int i16 = q * 256 + tid;
                *(int4*)(bb + i16 * 8) = *(const int4*)(src + i16 * 8);
            }
        }
        __syncthreads();
        #pragma unroll
        for (int s = 0; s < 2; ++s) {
            const short8 fa0 = *(const short8*)(ut + (0 * 32 + lo) * 40 + s * 16 + hi * 8);
            const short8 fa1 = *(const short8*)(ut + (1 * 32 + lo) * 40 + s * 16 + hi * 8);
            const short8 fb0 = *(const short8*)(bb + (((2 * w + 0) * 2 + s) * 64 + l) * 8);
            const short8 fb1 = *(const short8*)(bb + (((2 * w + 1) * 2 + s) * 64 + l) * 8);
            a00 = __builtin_amdgcn_mfma_f32_32x32x16_bf16(fa0, fb0, a00, 0, 0, 0);
            a01 = __builtin_amdgcn_mfma_f32_32x32x16_bf16(fa0, fb1, a01, 0, 0, 0);
            a10 = __builtin_amdgcn_mfma_f32_32x32x16_bf16(fa1, fb0, a10, 0, 0, 0);
            a11 = __builtin_amdgcn_mfma_f32_32x32x16_bf16(fa1, fb1, a11, 0, 0, 0);
        }
        __syncthreads();
    }
    #pragma unroll
    for (int tt = 0; tt < 2; ++tt)
        #pragma unroll
        for (int q = 0; q < 2; ++q) {
            const f32x16 a = (tt == 0) ? (q == 0 ? a00 : a01) : (q == 0 ? a10 : a11);
            const int n = (2 * w + q) * 32 + lo;
            #pragma unroll
            for (int g = 0; g < 4; ++g)
                #pragma unroll
                for (int p = 0; p < 2; ++p)
                    *(unsigned*)(xs + n * 66 + tt * 32 + hi * 4 + g * 8 + p * 2)
                        = f2bf(a[g * 4 + 2 * p]) | ((unsigned)f2bf(a[g * 4 + 2 * p + 1]) << 16);
        }
    __syncthreads();
}

__global__ __launch_bounds__(256) void k_phaseC_rc(
    const float* __restrict__ u, const unsigned short* __restrict__ BdKf,
    const unsigned short* __restrict__ CKf, const float* __restrict__ Ad,
    const float* __restrict__ carry, float* __restrict__ y)
{
    __shared__ __align__(16) unsigned short xs[16896];
    __shared__ __align__(16) unsigned short ut[2560];
    __shared__ __align__(16) unsigned short bb[8192];

    const int k = blockIdx.x, b = blockIdx.y;
    const int tid = threadIdx.x;
    const int w = tid >> 6, l = tid & 63, lo = l & 31, hi = l >> 5;
    const int t0 = k * L_;

    gemm1_rc(u, BdKf, b, k, xs, ut, bb);

    {
        const float a = Ad[tid];
        float s = carry[((size_t)k * B_ + b) * N_ + tid];
        float st[64];
        #pragma unroll
        for (int m = 0; m < 32; ++m) {
            const unsigned dw = *(const unsigned*)(xs + tid * 66 + 2 * m);
            s = fmaf(s, a, bf2f((unsigned short)(dw & 0xffff)));  st[2 * m] = s;
            s = fmaf(s, a, bf2f((unsigned short)(dw >> 16)));     st[2 * m + 1] = s;
        }
        __syncthreads();
        #pragma unroll
        for (int t = 0; t < 64; ++t) xs[t * 264 + tid] = f2bf(st[t]);
    }
    __syncthreads();

    f32x16 c00 = zero16(), c01 = zero16(), c10 = zero16(), c11 = zero16();
    for (int kk = 0; kk < 8; ++kk) {
        __syncthreads();
        {
            const unsigned short* src = CKf + kk * 8192;
            #pragma unroll
            for (int q = 0; q < 4; ++q) {
                const int i16 = q * 256 + tid;
                *(int4*)(bb + i16 * 8) = *(const int4*)(src + i16 * 8);
            }
        }
        __syncthreads();
        #pragma unroll
        for (int s = 0; s < 2; ++s) {
            const short8 fa0 = *(const short8*)(xs + (0 * 32 + lo) * 264 + kk * 32 + s * 16 + hi * 8);
            const short8 fa1 = *(const short8*)(xs + (1 * 32 + lo) * 264 + kk * 32 + s * 16 + hi * 8);
            const short8 fb0 = *(const short8*)(bb + (((2 * w + 0) * 2 + s) * 64 + l) * 8);
            const short8 fb1 = *(const short8*)(bb + (((2 * w + 1) * 2 + s) * 64 + l) * 8);
            c00 = __builtin_amdgcn_mfma_f32_32x32x16_bf16(fa0, fb0, c00, 0, 0, 0);
            c01 = __builtin_amdgcn_mfma_f32_32x32x16_bf16(fa0, fb1, c01, 0, 0, 0);
            c10 = __builtin_amdgcn_mfma_f32_32x32x16_bf16(fa1, fb0, c10, 0, 0, 0);
            c11 = __builtin_amdgcn_mfma_f32_32x32x16_bf16(fa1, fb1, c11, 0, 0, 0);
        }
    }

    #pragma unroll
    for (int tt = 0; tt < 2; ++tt)
        #pragma unroll
        for (int q = 0; q < 2; ++q) {
            const f32x16 a = (tt == 0) ? (q == 0 ? c00 : c01) : (q == 0 ? c10 : c11);
            const int o = (2 * w + q) * 32 + lo;
            float* yo = y + ((size_t)b * O_ + o) * T_ + t0 + tt * 32 + hi * 4;
            #pragma unroll
            for (int g = 0; g < 4; ++g) {
                float4 vv;
                vv.x = a[g * 4 + 0]; vv.y = a[g * 4 + 1];
                vv.z = a[g * 4 + 2]; vv.w = a[g * 4 + 3];
                *(float4*)(yo + g * 8) = vv;
            }
        }
}

// ---------------------------------------------------------------------------
extern "C" void kernel_launch(void* const* d_in, const int* in_sizes, int n_in,
                              void* d_out, int out_size, void* d_ws, size_t ws_size,
                              hipStream_t stream)
{
    const float* u  = (const float*)d_in[0];
    const float* rl = (const float*)d_in[1];
    const float* Bc = (const float*)d_in[2];
    const float* Cm = (const float*)d_in[3];
    float* y  = (float*)d_out;
    char*  ws = (char*)d_ws;

    float* Ad     = (float*)(ws + 0);
    float* AL     = (float*)(ws + 1024);
    float* p_last = (float*)(ws + 2048);
    float* carry  = (float*)(ws + 2048 + 2097152);
    unsigned short* BdKf = (unsigned short*)(ws + 2048 + 2 * 2097152);
    unsigned short* CKf  = (unsigned short*)(ws + 2048 + 2 * 2097152 + 131072);
    unsigned short* X    = (unsigned short*)(ws + 2048 + 2 * 2097152 + 2 * 131072);
    const size_t need = 2048 + 2ull * 2097152 + 2ull * 131072
                      + (size_t)NC_ * B_ * 32768;
    const int doX = (ws_size >= need) ? 1 : 0;

    k_prep  <<<dim3(256, 2),  dim3(256), 0, stream>>>(rl, Bc, Cm, Ad, AL, BdKf, CKf);
    k_phaseA<<<dim3(NC_, B_), dim3(256), 0, stream>>>(u, BdKf, Ad, p_last, X, doX);
    k_phaseB<<<dim3(B_),      dim3(256), 0, stream>>>(p_last, AL, carry);
    if (doX)
        k_phaseC<<<dim3(NC_, B_), dim3(256), 0, stream>>>(X, CKf, Ad, carry, y);
    else
        k_phaseC_rc<<<dim3(NC_, B_), dim3(256), 0, stream>>>(u, BdKf, CKf, Ad, carry, y);
}

// Round 13
// 100.894 us; speedup vs baseline: 1.0172x; 1.0172x over previous
//
#include <hip/hip_runtime.h>
#include <math.h>

typedef __attribute__((ext_vector_type(4)))  float f32x4;
typedef __attribute__((ext_vector_type(8)))  short short8;
typedef __attribute__((ext_vector_type(16))) float f32x16;

#define B_  16
#define C_  256
#define N_  256
#define O_  256
#define T_  8192
#define L_  64
#define NC_ 128

// async global->LDS, 16B per lane; lds base wave-uniform (HW adds lane*16)
#define GLL16(gptr, lptr) \
  __builtin_amdgcn_global_load_lds((const __attribute__((address_space(1))) void*)(gptr), \
                                   (__attribute__((address_space(3))) void*)(lptr), 16, 0, 0)

__device__ inline unsigned short f2bf(float x) {
    unsigned u = __float_as_uint(x);
    u += 0x7fff + ((u >> 16) & 1);
    return (unsigned short)(u >> 16);
}
__device__ inline float bf2f(unsigned short h) {
    return __uint_as_float(((unsigned)h) << 16);
}
__device__ inline unsigned cvtpk(float a, float b) {   // {lo:bf16(a), hi:bf16(b)}
    unsigned r;
    asm("v_cvt_pk_bf16_f32 %0, %1, %2" : "=v"(r) : "v"(a), "v"(b));
    return r;
}
__device__ inline f32x16 zero16() {
    f32x16 z;
    #pragma unroll
    for (int i = 0; i < 16; ++i) z[i] = 0.f;
    return z;
}

// ---------------------------------------------------------------------------
// prep: Ad, AL=Ad^64, MFMA b-fragment streams for Bd and C.
//   idx = (((kk*8 + nt)*2 + s)*64 + l)*8 + j
// ---------------------------------------------------------------------------
__global__ __launch_bounds__(256) void k_prep(
    const float* __restrict__ raw_lambda, const float* __restrict__ B_c,
    const float* __restrict__ Cmat,
    float* __restrict__ Ad, float* __restrict__ AL,
    unsigned short* __restrict__ BdKf, unsigned short* __restrict__ CKf)
{
    const int r = blockIdx.x;
    const int t = threadIdx.x;
    const int kk = r >> 5, ri = r & 31;
    const int s = ri >> 4, hi = (ri >> 3) & 1, j = ri & 7;
    const int nt = t >> 5, l = (hi << 5) | (t & 31);
    const int idx = (((kk * 8 + nt) * 2 + s) * 64 + l) * 8 + j;

    if (blockIdx.y == 0) {
        const float x  = raw_lambda[t];
        const float sp = (x > 20.f) ? x : log1pf(expf(x));
        const float lam = -sp;
        const float ad  = expf(lam);
        const float factor = (fabsf(lam) > 1e-6f) ? (ad - 1.f) / lam : 1.f;
        if (r == 0) {
            Ad[t] = ad;
            float al = ad;
            #pragma unroll
            for (int i = 0; i < 6; ++i) al *= al;
            AL[t] = al;
        }
        BdKf[idx] = f2bf(B_c[r * N_ + t] * factor);
    } else {
        CKf[idx] = f2bf(Cmat[r * O_ + t]);
    }
}

// B-frag direct-from-L2 load (lane-linear stream, coalesced 1 KB/wave-inst)
#define LDFRAG(MAT, kk, buf) { \
    _Pragma("unroll") \
    for (int q_ = 0; q_ < 2; ++q_) \
        _Pragma("unroll") \
        for (int s_ = 0; s_ < 2; ++s_) \
            fb[buf][q_ * 2 + s_] = *(const short8*)( \
                (MAT) + ((((kk) * 8 + 2 * w + q_) * 2 + s_) * 64 + l) * 8); }

// ---------------------------------------------------------------------------
// Phase A (v13): TWO chunks per block. All 32 NT float4 loads (both chunks)
// issue up front — chunk1's data streams in under pack0+GEMM0, raising the
// HBM read duty cycle. Single ut buffer; X0/p_last0 stores overlap GEMM1.
// ---------------------------------------------------------------------------
__global__ __launch_bounds__(256, 2) void k_phaseA(
    const float* __restrict__ u, const unsigned short* __restrict__ BdKf,
    const float* __restrict__ Ad, float* __restrict__ p_last,
    unsigned short* __restrict__ X, int doX)
{
    __shared__ __align__(16) unsigned short ut[16896];   // [64][264] swizzled

    const int k0 = blockIdx.x * 2, b = blockIdx.y;
    const int tid = threadIdx.x;
    const int w = tid >> 6, l = tid & 63, lo = l & 31, hi = l >> 5;
    const float* ub = u + (size_t)b * C_ * T_ + k0 * L_;

    const float adq0 = Ad[(2 * w + 0) * 32 + lo];
    const float adq1 = Ad[(2 * w + 1) * 32 + lo];

    // ---- issue ALL 32 NT float4 loads (chunk0 + chunk1) in one burst ----
    f32x4 va0[8], vb0[8], va1[8], vb1[8];
    #pragma unroll
    for (int q = 0; q < 8; ++q) {
        const int idx = q * 256 + tid;
        const int p = idx >> 4, t4 = idx & 15;       // c-pair, t-quad
        const float* base = ub + (size_t)(2 * p) * T_ + t4 * 4;
        va0[q] = __builtin_nontemporal_load((const f32x4*)(base));
        vb0[q] = __builtin_nontemporal_load((const f32x4*)(base + T_));
        va1[q] = __builtin_nontemporal_load((const f32x4*)(base + L_));
        vb1[q] = __builtin_nontemporal_load((const f32x4*)(base + T_ + L_));
    }

    auto pack = [&](const f32x4* va, const f32x4* vb) {
        unsigned* ud = (unsigned*)ut;
        #pragma unroll
        for (int q = 0; q < 8; ++q) {
            const int idx = q * 256 + tid;
            const int p = idx >> 4, t4 = idx & 15;
            const int nb = p >> 2, jd = p & 3;
            #pragma unroll
            for (int r = 0; r < 4; ++r) {
                const int tA = 4 * t4 + r;
                const int xsw = (tA >> 3) & 3;
                ud[tA * 132 + (((nb ^ xsw) << 2) | jd)] = cvtpk(va[q][r], vb[q][r]);
            }
        }
    };

    auto gemm = [&](f32x16& a00, f32x16& a01, f32x16& a10, f32x16& a11) {
        short8 fb[3][4];
        LDFRAG(BdKf, 0, 0)
        LDFRAG(BdKf, 1, 1)
        #pragma unroll
        for (int kk = 0; kk < 8; ++kk) {
            if (kk < 6) LDFRAG(BdKf, kk + 2, (kk + 2) % 3)
            #pragma unroll
            for (int s = 0; s < 2; ++s) {
                const int blk8 = kk * 4 + s * 2 + hi;
                const int tA2 = lo, tB2 = 32 + lo;
                const short8 fa0 = *(const short8*)(ut + tA2 * 264 + ((blk8 ^ ((tA2 >> 3) & 3)) << 3));
                const short8 fa1 = *(const short8*)(ut + tB2 * 264 + ((blk8 ^ ((tB2 >> 3) & 3)) << 3));
                const short8 fb0 = fb[kk % 3][0 * 2 + s];
                const short8 fb1 = fb[kk % 3][1 * 2 + s];
                a00 = __builtin_amdgcn_mfma_f32_32x32x16_bf16(fa0, fb0, a00, 0, 0, 0);
                a01 = __builtin_amdgcn_mfma_f32_32x32x16_bf16(fa0, fb1, a01, 0, 0, 0);
                a10 = __builtin_amdgcn_mfma_f32_32x32x16_bf16(fa1, fb0, a10, 0, 0, 0);
                a11 = __builtin_amdgcn_mfma_f32_32x32x16_bf16(fa1, fb1, a11, 0, 0, 0);
            }
        }
    };

    auto xstore = [&](const f32x16& a00, const f32x16& a01,
                      const f32x16& a10, const f32x16& a11, int k) {
        unsigned* Xd = (unsigned*)X + (size_t)(k * B_ + b) * 8192;
        #pragma unroll
        for (int f = 0; f < 4; ++f) {
            const f32x16& a = (f == 0) ? a00 : (f == 1) ? a01 : (f == 2) ? a10 : a11;
            unsigned dw[8];
            #pragma unroll
            for (int d = 0; d < 8; ++d)
                dw[d] = cvtpk(a[2 * d], a[2 * d + 1]);
            unsigned* base = Xd + w * 2048 + f * 512 + l * 4;
            *(int4*)(base)       = *(const int4*)&dw[0];
            *(int4*)(base + 256) = *(const int4*)&dw[4];
        }
    };

    // row map: t = tt*32 + (reg&3) + 8*(reg>>2) + 4*hi
    auto plast = [&](const f32x16& a00, const f32x16& a01,
                     const f32x16& a10, const f32x16& a11, int k) {
        float p[2];
        #pragma unroll
        for (int q = 0; q < 2; ++q) {
            const float ad = q ? adq1 : adq0;
            const float ad2 = ad * ad, ad4 = ad2 * ad2, ad8 = ad4 * ad4;
            const float ad16 = ad8 * ad8, ad32 = ad16 * ad16;
            float full[2];
            #pragma unroll
            for (int tt = 0; tt < 2; ++tt) {
                const f32x16& a = (tt == 0) ? (q == 0 ? a00 : a01)
                                            : (q == 0 ? a10 : a11);
                float v2[4];
                #pragma unroll
                for (int g = 0; g < 4; ++g)
                    v2[g] = fmaf(fmaf(fmaf(a[4*g], ad, a[4*g+1]), ad, a[4*g+2]), ad, a[4*g+3]);
                const float H = fmaf(fmaf(fmaf(v2[0], ad8, v2[1]), ad8, v2[2]), ad8, v2[3]);
                float P = hi ? H : H * ad4;
                P += __shfl_xor(P, 32);
                full[tt] = P;
            }
            p[q] = fmaf(full[0], ad32, full[1]);
        }
        if (hi == 0) {
            float* dst = p_last + (size_t)(k * B_ + b) * N_;
            dst[(2 * w + 0) * 32 + lo] = p[0];
            dst[(2 * w + 1) * 32 + lo] = p[1];
        }
    };

    // ---- chunk 0 ----
    pack(va0, vb0);
    __syncthreads();
    f32x16 a00 = zero16(), a01 = zero16(), a10 = zero16(), a11 = zero16();
    gemm(a00, a01, a10, a11);
    __syncthreads();          // GEMM0's ut reads done before pack1 overwrites

    // ---- chunk 1 staging, then chunk0 epilogue overlapping GEMM1 ----
    pack(va1, vb1);
    __syncthreads();
    if (doX) xstore(a00, a01, a10, a11, k0);
    plast(a00, a01, a10, a11, k0);

    f32x16 c00 = zero16(), c01 = zero16(), c10 = zero16(), c11 = zero16();
    gemm(c00, c01, c10, c11);
    if (doX) xstore(c00, c01, c10, c11, k0 + 1);
    plast(c00, c01, c10, c11, k0 + 1);
}

// ---------------------------------------------------------------------------
// Phase B: carry scan over chunks, LDS-prefetched.
// ---------------------------------------------------------------------------
__global__ __launch_bounds__(256) void k_phaseB(
    const float* __restrict__ p_last, const float* __restrict__ AL,
    float* __restrict__ carry)
{
    __shared__ float buf[32 * 256];
    const int b = blockIdx.x, n = threadIdx.x;
    const float al = AL[n];
    float cur = 0.f;
    for (int kc = 0; kc < 4; ++kc) {
        __syncthreads();
        #pragma unroll
        for (int q = 0; q < 32; ++q)
            buf[q * 256 + n] = p_last[((size_t)(kc * 32 + q) * B_ + b) * N_ + n];
        __syncthreads();
        #pragma unroll
        for (int q = 0; q < 32; ++q) {
            carry[((size_t)(kc * 32 + q) * B_ + b) * N_ + n] = cur;
            cur = fmaf(cur, al, buf[q * 256 + n]);
        }
    }
}

// ---------------------------------------------------------------------------
// Phase C (v13 = v11 unchanged): GLL16 X -> LDS; column gather; scan ->
// swizzled states (in place); barrier-free GEMM2 with direct L2 C-frag loads.
// ---------------------------------------------------------------------------
__global__ __launch_bounds__(256, 3) void k_phaseC(
    const unsigned short* __restrict__ X, const unsigned short* __restrict__ CKf,
    const float* __restrict__ Ad, const float* __restrict__ carry,
    float* __restrict__ y)
{
    __shared__ __align__(16) unsigned short xs[16896];  // X image -> states [64][264]

    const int k = blockIdx.x, b = blockIdx.y;
    const int tid = threadIdx.x;
    const int w = tid >> 6, l = tid & 63, lo = l & 31, hi = l >> 5;
    const int t0 = k * L_;

    {
        const char* src = (const char*)X + (size_t)(k * B_ + b) * 32768;
        #pragma unroll
        for (int q = 0; q < 8; ++q)
            GLL16(src + q * 4096 + w * 1024 + (l << 4),
                  (char*)xs + q * 4096 + w * 1024);
    }
    const float cv = carry[(size_t)(k * B_ + b) * N_ + tid];
    const float ad = Ad[tid];
    __syncthreads();

    // gather this thread's column (n = tid) from frag-layout X
    unsigned arr[2][2][8];   // [tt][h][dw]
    {
        const unsigned* xd = (const unsigned*)xs;
        const int w2 = tid >> 6, q2 = (tid >> 5) & 1, lo2 = tid & 31;
        #pragma unroll
        for (int tt = 0; tt < 2; ++tt)
            #pragma unroll
            for (int h2 = 0; h2 < 2; ++h2) {
                const unsigned* p = xd + w2 * 2048 + (tt * 2 + q2) * 512
                                       + (h2 * 32 + lo2) * 4;
                *(int4*)&arr[tt][h2][0] = *(const int4*)(p);
                *(int4*)&arr[tt][h2][4] = *(const int4*)(p + 256);
            }
    }
    __syncthreads();   // all X reads done before states overwrite

    // scan + write states [64][264] with col-block XOR swizzle
    {
        const int nb = tid >> 3, nl = tid & 7;
        float s = cv;
        #pragma unroll
        for (int tt = 0; tt < 2; ++tt)
            #pragma unroll
            for (int g = 0; g < 4; ++g)
                #pragma unroll
                for (int h2 = 0; h2 < 2; ++h2) {
                    const unsigned d0 = arr[tt][h2][2 * g];
                    const unsigned d1 = arr[tt][h2][2 * g + 1];
                    const int tb = tt * 32 + 8 * g + 4 * h2;
                    const int swz = (((nb ^ ((tb >> 3) & 3)) << 3) | nl);
                    s = fmaf(s, ad, bf2f((unsigned short)(d0 & 0xffff)));
                    xs[(tb + 0) * 264 + swz] = f2bf(s);
                    s = fmaf(s, ad, bf2f((unsigned short)(d0 >> 16)));
                    xs[(tb + 1) * 264 + swz] = f2bf(s);
                    s = fmaf(s, ad, bf2f((unsigned short)(d1 & 0xffff)));
                    xs[(tb + 2) * 264 + swz] = f2bf(s);
                    s = fmaf(s, ad, bf2f((unsigned short)(d1 >> 16)));
                    xs[(tb + 3) * 264 + swz] = f2bf(s);
                }
    }
    __syncthreads();

    // ---- GEMM2: barrier-free; C-frags direct from L2, 2-ahead prefetch ----
    f32x16 c00 = zero16(), c01 = zero16(), c10 = zero16(), c11 = zero16();
    {
        short8 fb[3][4];
        LDFRAG(CKf, 0, 0)
        LDFRAG(CKf, 1, 1)
        #pragma unroll
        for (int kk = 0; kk < 8; ++kk) {
            if (kk < 6) LDFRAG(CKf, kk + 2, (kk + 2) % 3)
            #pragma unroll
            for (int s = 0; s < 2; ++s) {
                short8 fa[2];
                #pragma unroll
                for (int tt = 0; tt < 2; ++tt) {
                    const int t = tt * 32 + lo;
                    const int blk = (kk * 4 + s * 2 + hi) ^ ((t >> 3) & 3);
                    fa[tt] = *(const short8*)(xs + t * 264 + blk * 8);
                }
                const short8 fb0 = fb[kk % 3][0 * 2 + s];
                const short8 fb1 = fb[kk % 3][1 * 2 + s];
                c00 = __builtin_amdgcn_mfma_f32_32x32x16_bf16(fa[0], fb0, c00, 0, 0, 0);
                c01 = __builtin_amdgcn_mfma_f32_32x32x16_bf16(fa[0], fb1, c01, 0, 0, 0);
                c10 = __builtin_amdgcn_mfma_f32_32x32x16_bf16(fa[1], fb0, c10, 0, 0, 0);
                c11 = __builtin_amdgcn_mfma_f32_32x32x16_bf16(fa[1], fb1, c11, 0, 0, 0);
            }
        }
    }

    // ---- y store ----
    #pragma unroll
    for (int tt = 0; tt < 2; ++tt)
        #pragma unroll
        for (int q = 0; q < 2; ++q) {
            const f32x16 a = (tt == 0) ? (q == 0 ? c00 : c01) : (q == 0 ? c10 : c11);
            const int o = (2 * w + q) * 32 + lo;
            float* yo = y + ((size_t)b * O_ + o) * T_ + t0 + tt * 32 + hi * 4;
            #pragma unroll
            for (int g = 0; g < 4; ++g) {
                float4 vv;
                vv.x = a[g * 4 + 0]; vv.y = a[g * 4 + 1];
                vv.z = a[g * 4 + 2]; vv.w = a[g * 4 + 3];
                *(float4*)(yo + g * 8) = vv;
            }
        }
}

// ---------------------------------------------------------------------------
// Fallback Phase C (recompute GEMM1) — used only if ws too small.
// ---------------------------------------------------------------------------
__device__ __forceinline__ void gemm1_rc(
    const float* __restrict__ u, const unsigned short* __restrict__ BdKf,
    int b, int k, unsigned short* xs, unsigned short* ut, unsigned short* bb)
{
    const int tid = threadIdx.x;
    const int w = tid >> 6, l = tid & 63, lo = l & 31, hi = l >> 5;
    const int t0 = k * L_;
    f32x16 a00 = zero16(), a01 = zero16(), a10 = zero16(), a11 = zero16();
    for (int kk = 0; kk < 8; ++kk) {
        #pragma unroll
        for (int q = 0; q < 2; ++q) {
            const int i = q * 256 + tid, cl = i >> 4, t4 = i & 15;
            const float4 v = *(const float4*)(
                u + ((size_t)b * C_ + kk * 32 + cl) * T_ + t0 + t4 * 4);
            ut[(t4 * 4 + 0) * 40 + cl] = f2bf(v.x);
            ut[(t4 * 4 + 1) * 40 + cl] = f2bf(v.y);
            ut[(t4 * 4 + 2) * 40 + cl] = f2bf(v.z);
            ut[(t4 * 4 + 3) * 40 + cl] = f2bf(v.w);
        }
        {
            const unsigned short* src = BdKf + kk * 8192;
            #pragma unroll
            for (int q = 0; q < 4; ++q) {
                const int i16 = q * 256 + tid;
                *(int4*)(bb + i16 * 8) = *(const int4*)(src + i16 * 8);
            }
        }
        __syncthreads();
        #pragma unroll
        for (int s = 0; s < 2; ++s) {
            const short8 fa0 = *(const short8*)(ut + (0 * 32 + lo) * 40 + s * 16 + hi * 8);
            const short8 fa1 = *(const short8*)(ut + (1 * 32 + lo) * 40 + s * 16 + hi * 8);
            const short8 fb0 = *(const short8*)(bb + (((2 * w + 0) * 2 + s) * 64 + l) * 8);
            const short8 fb1 = *(const short8*)(bb + (((2 * w + 1) * 2 + s) * 64 + l) * 8);
            a00 = __builtin_amdgcn_mfma_f32_32x32x16_bf16(fa0, fb0, a00, 0, 0, 0);
            a01 = __builtin_amdgcn_mfma_f32_32x32x16_bf16(fa0, fb1, a01, 0, 0, 0);
            a10 = __builtin_amdgcn_mfma_f32_32x32x16_bf16(fa1, fb0, a10, 0, 0, 0);
            a11 = __builtin_amdgcn_mfma_f32_32x32x16_bf16(fa1, fb1, a11, 0, 0, 0);
        }
        __syncthreads();
    }
    #pragma unroll
    for (int tt = 0; tt < 2; ++tt)
        #pragma unroll
        for (int q = 0; q < 2; ++q) {
            const f32x16 a = (tt == 0) ? (q == 0 ? a00 : a01) : (q == 0 ? a10 : a11);
            const int n = (2 * w + q) * 32 + lo;
            #pragma unroll
            for (int g = 0; g < 4; ++g)
                #pragma unroll
                for (int p = 0; p < 2; ++p)
                    *(unsigned*)(xs + n * 66 + tt * 32 + hi * 4 + g * 8 + p * 2)
                        = f2bf(a[g * 4 + 2 * p]) | ((unsigned)f2bf(a[g * 4 + 2 * p + 1]) << 16);
        }
    __syncthreads();
}

__global__ __launch_bounds__(256) void k_phaseC_rc(
    const float* __restrict__ u, const unsigned short* __restrict__ BdKf,
    const unsigned short* __restrict__ CKf, const float* __restrict__ Ad,
    const float* __restrict__ carry, float* __restrict__ y)
{
    __shared__ __align__(16) unsigned short xs[16896];
    __shared__ __align__(16) unsigned short ut[2560];
    __shared__ __align__(16) unsigned short bb[8192];

    const int k = blockIdx.x, b = blockIdx.y;
    const int tid = threadIdx.x;
    const int w = tid >> 6, l = tid & 63, lo = l & 31, hi = l >> 5;
    const int t0 = k * L_;

    gemm1_rc(u, BdKf, b, k, xs, ut, bb);

    {
        const float a = Ad[tid];
        float s = carry[((size_t)k * B_ + b) * N_ + tid];
        float st[64];
        #pragma unroll
        for (int m = 0; m < 32; ++m) {
            const unsigned dw = *(const unsigned*)(xs + tid * 66 + 2 * m);
            s = fmaf(s, a, bf2f((unsigned short)(dw & 0xffff)));  st[2 * m] = s;
            s = fmaf(s, a, bf2f((unsigned short)(dw >> 16)));     st[2 * m + 1] = s;
        }
        __syncthreads();
        #pragma unroll
        for (int t = 0; t < 64; ++t) xs[t * 264 + tid] = f2bf(st[t]);
    }
    __syncthreads();

    f32x16 c00 = zero16(), c01 = zero16(), c10 = zero16(), c11 = zero16();
    for (int kk = 0; kk < 8; ++kk) {
        __syncthreads();
        {
            const unsigned short* src = CKf + kk * 8192;
            #pragma unroll
            for (int q = 0; q < 4; ++q) {
                const int i16 = q * 256 + tid;
                *(int4*)(bb + i16 * 8) = *(const int4*)(src + i16 * 8);
            }
        }
        __syncthreads();
        #pragma unroll
        for (int s = 0; s < 2; ++s) {
            const short8 fa0 = *(const short8*)(xs + (0 * 32 + lo) * 264 + kk * 32 + s * 16 + hi * 8);
            const short8 fa1 = *(const short8*)(xs + (1 * 32 + lo) * 264 + kk * 32 + s * 16 + hi * 8);
            const short8 fb0 = *(const short8*)(bb + (((2 * w + 0) * 2 + s) * 64 + l) * 8);
            const short8 fb1 = *(const short8*)(bb + (((2 * w + 1) * 2 + s) * 64 + l) * 8);
            c00 = __builtin_amdgcn_mfma_f32_32x32x16_bf16(fa0, fb0, c00, 0, 0, 0);
            c01 = __builtin_amdgcn_mfma_f32_32x32x16_bf16(fa0, fb1, c01, 0, 0, 0);
            c10 = __builtin_amdgcn_mfma_f32_32x32x16_bf16(fa1, fb0, c10, 0, 0, 0);
            c11 = __builtin_amdgcn_mfma_f32_32x32x16_bf16(fa1, fb1, c11, 0, 0, 0);
        }
    }

    #pragma unroll
    for (int tt = 0; tt < 2; ++tt)
        #pragma unroll
        for (int q = 0; q < 2; ++q) {
            const f32x16 a = (tt == 0) ? (q == 0 ? c00 : c01) : (q == 0 ? c10 : c11);
            const int o = (2 * w + q) * 32 + lo;
            float* yo = y + ((size_t)b * O_ + o) * T_ + t0 + tt * 32 + hi * 4;
            #pragma unroll
            for (int g = 0; g < 4; ++g) {
                float4 vv;
                vv.x = a[g * 4 + 0]; vv.y = a[g * 4 + 1];
                vv.z = a[g * 4 + 2]; vv.w = a[g * 4 + 3];
                *(float4*)(yo + g * 8) = vv;
            }
        }
}

// ---------------------------------------------------------------------------
extern "C" void kernel_launch(void* const* d_in, const int* in_sizes, int n_in,
                              void* d_out, int out_size, void* d_ws, size_t ws_size,
                              hipStream_t stream)
{
    const float* u  = (const float*)d_in[0];
    const float* rl = (const float*)d_in[1];
    const float* Bc = (const float*)d_in[2];
    const float* Cm = (const float*)d_in[3];
    float* y  = (float*)d_out;
    char*  ws = (char*)d_ws;

    float* Ad     = (float*)(ws + 0);
    float* AL     = (float*)(ws + 1024);
    float* p_last = (float*)(ws + 2048);
    float* carry  = (float*)(ws + 2048 + 2097152);
    unsigned short* BdKf = (unsigned short*)(ws + 2048 + 2 * 2097152);
    unsigned short* CKf  = (unsigned short*)(ws + 2048 + 2 * 2097152 + 131072);
    unsigned short* X    = (unsigned short*)(ws + 2048 + 2 * 2097152 + 2 * 131072);
    const size_t need = 2048 + 2ull * 2097152 + 2ull * 131072
                      + (size_t)NC_ * B_ * 32768;
    const int doX = (ws_size >= need) ? 1 : 0;

    k_prep  <<<dim3(256, 2),  dim3(256), 0, stream>>>(rl, Bc, Cm, Ad, AL, BdKf, CKf);
    if (doX) {
        k_phaseA<<<dim3(NC_ / 2, B_), dim3(256), 0, stream>>>(u, BdKf, Ad, p_last, X, doX);
        k_phaseB<<<dim3(B_),          dim3(256), 0, stream>>>(p_last, AL, carry);
        k_phaseC<<<dim3(NC_, B_),     dim3(256), 0, stream>>>(X, CKf, Ad, carry, y);
    } else {
        k_phaseA<<<dim3(NC_ / 2, B_), dim3(256), 0, stream>>>(u, BdKf, Ad, p_last, X, doX);
        k_phaseB<<<dim3(B_),          dim3(256), 0, stream>>>(p_last, AL, carry);
        k_phaseC_rc<<<dim3(NC_, B_),  dim3(256), 0, stream>>>(u, BdKf, CKf, Ad, carry, y);
    }
}